// Round 1
// baseline (210.256 us; speedup 1.0000x reference)
//
#include <hip/hip_runtime.h>
#include <math.h>

#define Bc 32
#define Cc 64
#define Tc 128
#define Vc 25
#define OUTC 64
#define RELC 8
#define TSC 9

// ---------------- K1: xm[b,c,v] = mean_t x[b,c,t,v] ----------------
__global__ __launch_bounds__(256) void k_mean(const float* __restrict__ x,
                                              float* __restrict__ xm) {
    int bc = blockIdx.x;                 // 0..B*C-1
    int v  = threadIdx.x & 31;           // 0..31 (v < 25 active)
    int tg = threadIdx.x >> 5;           // 0..7
    const float* xp = x + (size_t)bc * Tc * Vc;
    float s = 0.f;
    if (v < Vc) {
        for (int t = tg; t < Tc; t += 8) s += xp[t * Vc + v];
    }
    __shared__ float red[8][32];
    red[tg][v] = s;
    __syncthreads();
    if (tg == 0 && v < Vc) {
        float tot = 0.f;
#pragma unroll
        for (int g = 0; g < 8; ++g) tot += red[g][v];
        xm[bc * Vc + v] = tot * (1.0f / Tc);
    }
}

// ---------------- K2: d[b,r,j,i] = tanh(x1[b,r,j] - x2[b,r,i]) ----------------
__global__ __launch_bounds__(256) void k_rel(const float* __restrict__ xm,
                                             const float* __restrict__ w1,
                                             const float* __restrict__ b1,
                                             const float* __restrict__ w2,
                                             const float* __restrict__ b2,
                                             float* __restrict__ d) {
    int b = blockIdx.x;
    __shared__ float sxm[Cc * Vc];       // 1600
    __shared__ float sx1[RELC * Vc];     // 200
    __shared__ float sx2[RELC * Vc];     // 200
    int tid = threadIdx.x;
    for (int idx = tid; idx < Cc * Vc; idx += 256)
        sxm[idx] = xm[(size_t)b * Cc * Vc + idx];
    __syncthreads();
    for (int idx = tid; idx < 2 * RELC * Vc; idx += 256) {
        int which = idx / (RELC * Vc);
        int rv = idx % (RELC * Vc);
        int r = rv / Vc, v = rv % Vc;
        const float* w = which ? w2 : w1;
        float acc = which ? b2[r] : b1[r];
        for (int c = 0; c < Cc; ++c) acc += w[r * Cc + c] * sxm[c * Vc + v];
        (which ? sx2 : sx1)[rv] = acc;
    }
    __syncthreads();
    float* dp = d + (size_t)b * RELC * Vc * Vc;
    for (int idx = tid; idx < RELC * Vc * Vc; idx += 256) {
        int r  = idx / (Vc * Vc);
        int jj = (idx / Vc) % Vc;
        int ii = idx % Vc;
        dp[idx] = tanhf(sx1[r * Vc + jj] - sx2[r * Vc + ii]);
    }
}

// ---------------- K3: z[b,c,t,i] = sum_{k,j} xpad[b,c,t+k,j] * W[b,c,j,i,k] ----
// W[j,i,k] = sum_r w4[c*TS+k, r] * d[b,r,j,i] + b4[c*TS+k] + A[j,i]
__global__ __launch_bounds__(256) void k_dynconv(const float* __restrict__ x,
                                                 const float* __restrict__ d,
                                                 const float* __restrict__ w4,
                                                 const float* __restrict__ b4,
                                                 const float* __restrict__ A,
                                                 float* __restrict__ z) {
    int bc = blockIdx.x;
    int b = bc / Cc, c = bc % Cc;
    __shared__ float xs[(Tc + TSC - 1) * Vc];  // 136*25 = 3400 floats
    __shared__ float sW[TSC * Vc * Vc];        // [k][j][i], 5625 floats
    __shared__ float sw4[TSC * RELC];          // 72 floats
    int tid = threadIdx.x;

    // stage x with TS-1 zero rows on the left (causal pad)
    const float* xp = x + (size_t)bc * Tc * Vc;
    for (int idx = tid; idx < (Tc + TSC - 1) * Vc; idx += 256) {
        int row = idx / Vc;
        xs[idx] = (row < TSC - 1) ? 0.f : xp[idx - (TSC - 1) * Vc];
    }
    if (tid < TSC * RELC)
        sw4[tid] = w4[(c * TSC + (tid >> 3)) * RELC + (tid & 7)];
    __syncthreads();

    // build W in LDS
    const float* dp = d + (size_t)b * RELC * Vc * Vc;
    for (int idx = tid; idx < TSC * Vc * Vc; idx += 256) {
        int k  = idx / (Vc * Vc);
        int ji = idx % (Vc * Vc);
        float acc = b4[c * TSC + k] + A[ji];
#pragma unroll
        for (int r = 0; r < RELC; ++r)
            acc += sw4[k * RELC + r] * dp[r * Vc * Vc + ji];
        sW[k * Vc * Vc + ji] = acc;
    }
    __syncthreads();

    // z: thread = (i = tid&31, tg = tid>>5); 16 consecutive t per thread
    int i = tid & 31, tg = tid >> 5;
    if (i < Vc) {
        float acc[16];
#pragma unroll
        for (int s = 0; s < 16; ++s) acc[s] = 0.f;
        int t0 = tg * 16;
        for (int j = 0; j < Vc; ++j) {
            float xr[16 + TSC - 1];  // 24 rows of column j
#pragma unroll
            for (int m = 0; m < 16 + TSC - 1; ++m)
                xr[m] = xs[(t0 + m) * Vc + j];
#pragma unroll
            for (int k = 0; k < TSC; ++k) {
                float w = sW[(k * Vc + j) * Vc + i];
#pragma unroll
                for (int s = 0; s < 16; ++s) acc[s] += xr[s + k] * w;
            }
        }
        float* zp = z + (size_t)bc * Tc * Vc;
#pragma unroll
        for (int s = 0; s < 16; ++s) zp[(t0 + s) * Vc + i] = acc[s];
    }
}

// ---------------- K4: out[b,o,t,v] = sum_c w3[o,c]*z[b,c,t,v] + b3[o] ---------
__global__ __launch_bounds__(256) void k_conv3(const float* __restrict__ z,
                                               const float* __restrict__ w3,
                                               const float* __restrict__ b3,
                                               float* __restrict__ out) {
    int b = blockIdx.y;
    int col = blockIdx.x * 256 + threadIdx.x;  // 0..T*V-1 (3200)
    __shared__ float sw3[OUTC * Cc];           // 4096 floats
    for (int idx = threadIdx.x; idx < OUTC * Cc; idx += 256) sw3[idx] = w3[idx];
    __syncthreads();
    if (col >= Tc * Vc) return;
    const float* zp = z + (size_t)b * Cc * Tc * Vc + col;
    float acc[OUTC];
#pragma unroll
    for (int o = 0; o < OUTC; ++o) acc[o] = b3[o];
    for (int c = 0; c < Cc; ++c) {
        float zv = zp[(size_t)c * Tc * Vc];
#pragma unroll
        for (int o = 0; o < OUTC; ++o) acc[o] += sw3[o * Cc + c] * zv;
    }
    float* op = out + (size_t)b * OUTC * Tc * Vc + col;
#pragma unroll
    for (int o = 0; o < OUTC; ++o) op[(size_t)o * Tc * Vc] = acc[o];
}

extern "C" void kernel_launch(void* const* d_in, const int* in_sizes, int n_in,
                              void* d_out, int out_size, void* d_ws, size_t ws_size,
                              hipStream_t stream) {
    const float* x  = (const float*)d_in[0];
    const float* A  = (const float*)d_in[1];
    const float* w1 = (const float*)d_in[2];
    const float* b1 = (const float*)d_in[3];
    const float* w2 = (const float*)d_in[4];
    const float* b2 = (const float*)d_in[5];
    const float* w3 = (const float*)d_in[6];
    const float* b3 = (const float*)d_in[7];
    const float* w4 = (const float*)d_in[8];
    const float* b4 = (const float*)d_in[9];
    float* out = (float*)d_out;

    float* ws = (float*)d_ws;
    float* xm = ws;                                  // B*C*V      = 51200
    float* dd = ws + (size_t)Bc * Cc * Vc;           // B*R*V*V    = 160000
    float* zz = dd + (size_t)Bc * RELC * Vc * Vc;    // B*C*T*V    = 6553600

    k_mean<<<Bc * Cc, 256, 0, stream>>>(x, xm);
    k_rel<<<Bc, 256, 0, stream>>>(xm, w1, b1, w2, b2, dd);
    k_dynconv<<<Bc * Cc, 256, 0, stream>>>(x, dd, w4, b4, A, zz);
    k_conv3<<<dim3(13, Bc), 256, 0, stream>>>(zz, w3, b3, out);
}

// Round 2
// 134.214 us; speedup vs baseline: 1.5666x; 1.5666x over previous
//
#include <hip/hip_runtime.h>
#include <math.h>

#define Bc 32
#define Cc 64
#define Tc 128
#define Vc 25
#define OUTC 64
#define RELC 8
#define TSC 9

typedef __bf16 bf16x8 __attribute__((ext_vector_type(8)));
typedef float f32x4 __attribute__((ext_vector_type(4)));

static __device__ __forceinline__ ushort f2bf(float f) {
    union { float f; uint u; } v; v.f = f;
    uint u = v.u;
    u += 0x7fff + ((u >> 16) & 1);   // RNE
    return (ushort)(u >> 16);
}

// load 8 bf16 (4 dwords) from an LDS row at dword offset dwoff; rows are
// padded to odd dword strides so the 4 b32 phases are ~2-way (free) on banks
static __device__ __forceinline__ bf16x8 ldfrag(const ushort* row, int dwoff) {
    const uint* p = (const uint*)row + dwoff;
    uint4 u;
    u.x = p[0]; u.y = p[1]; u.z = p[2]; u.w = p[3];
    return __builtin_bit_cast(bf16x8, u);
}

// ---------------- K1: xm[b,c,v] = mean_t x[b,c,t,v] ----------------
__global__ __launch_bounds__(256) void k_mean(const float* __restrict__ x,
                                              float* __restrict__ xm) {
    int bc = blockIdx.x;
    int v  = threadIdx.x & 31;
    int tg = threadIdx.x >> 5;
    const float* xp = x + (size_t)bc * Tc * Vc;
    float s = 0.f;
    if (v < Vc) {
        for (int t = tg; t < Tc; t += 8) s += xp[t * Vc + v];
    }
    __shared__ float red[8][32];
    red[tg][v] = s;
    __syncthreads();
    if (tg == 0 && v < Vc) {
        float tot = 0.f;
#pragma unroll
        for (int g = 0; g < 8; ++g) tot += red[g][v];
        xm[bc * Vc + v] = tot * (1.0f / Tc);
    }
}

// ---------------- K2: d[b,r,j,i] = tanh(x1[b,r,j] - x2[b,r,i]) ----------------
__global__ __launch_bounds__(256) void k_rel(const float* __restrict__ xm,
                                             const float* __restrict__ w1,
                                             const float* __restrict__ b1,
                                             const float* __restrict__ w2,
                                             const float* __restrict__ b2,
                                             float* __restrict__ d) {
    int b = blockIdx.x;
    __shared__ float sxm[Cc * Vc];
    __shared__ float sx1[RELC * Vc];
    __shared__ float sx2[RELC * Vc];
    int tid = threadIdx.x;
    for (int idx = tid; idx < Cc * Vc; idx += 256)
        sxm[idx] = xm[(size_t)b * Cc * Vc + idx];
    __syncthreads();
    for (int idx = tid; idx < 2 * RELC * Vc; idx += 256) {
        int which = idx / (RELC * Vc);
        int rv = idx % (RELC * Vc);
        int r = rv / Vc, v = rv % Vc;
        const float* w = which ? w2 : w1;
        float acc = which ? b2[r] : b1[r];
        for (int c = 0; c < Cc; ++c) acc += w[r * Cc + c] * sxm[c * Vc + v];
        (which ? sx2 : sx1)[rv] = acc;
    }
    __syncthreads();
    float* dp = d + (size_t)b * RELC * Vc * Vc;
    for (int idx = tid; idx < RELC * Vc * Vc; idx += 256) {
        int r  = idx / (Vc * Vc);
        int jj = (idx / Vc) % Vc;
        int ii = idx % Vc;
        dp[idx] = tanhf(sx1[r * Vc + jj] - sx2[r * Vc + ii]);
    }
}

// ---------------- K3: dynconv via MFMA over 9 shifted GEMMs -------------------
// z[t,i] = sum_k sum_j xs[t+k, j] * W[j,i,k]; one 16x16x32 K-step per shift k.
#define XSROW 38     // 19 dwords: odd-dword row stride -> ~2-way banks
#define XSROWS 136
__global__ __launch_bounds__(256, 4) void k_dynconv(const float* __restrict__ x,
                                                    const float* __restrict__ d,
                                                    const float* __restrict__ w4,
                                                    const float* __restrict__ b4,
                                                    const float* __restrict__ A,
                                                    ushort* __restrict__ z) {
    int bc = blockIdx.x;
    int b = bc / Cc, c = bc % Cc;
    __shared__ ushort xs[XSROWS * XSROW];     // 10.3 KB, padded x in bf16
    __shared__ ushort sB[TSC * 32 * XSROW];   // 21.9 KB, W[j,i,k] as [k][i][j]
    __shared__ float sw4[TSC * RELC];
    __shared__ float sb4[TSC];
    int tid = threadIdx.x;

    // phase 1: zero sB; stage xs (bf16 pairs); load w4/b4 slices
    uint* sBu = (uint*)sB;
    for (int idx = tid; idx < TSC * 32 * (XSROW / 2); idx += 256) sBu[idx] = 0;
    const float* xp = x + (size_t)bc * Tc * Vc;
    uint* xsu = (uint*)xs;
    for (int idx = tid; idx < XSROWS * (XSROW / 2); idx += 256) {
        int row = idx / (XSROW / 2), pr = idx % (XSROW / 2);
        int j0 = pr * 2;
        float f0 = 0.f, f1 = 0.f;
        if (row >= TSC - 1) {
            const float* xr = xp + (row - (TSC - 1)) * Vc;
            if (j0 < Vc) f0 = xr[j0];
            if (j0 + 1 < Vc) f1 = xr[j0 + 1];
        }
        xsu[idx] = (uint)f2bf(f0) | ((uint)f2bf(f1) << 16);
    }
    if (tid < TSC * RELC) sw4[tid] = w4[(c * TSC + tid / RELC) * RELC + tid % RELC];
    if (tid < TSC) sb4[tid] = b4[c * TSC + tid];
    __syncthreads();

    // phase 2: build sB[k][i][j] = b4 + A[j,i] + sum_r w4[k,r]*d[r,j,i]
    const float* dp = d + (size_t)b * RELC * Vc * Vc;
    for (int p = tid; p < Vc * Vc; p += 256) {
        int j = p / Vc, i = p % Vc;
        float dv[RELC];
#pragma unroll
        for (int r = 0; r < RELC; ++r) dv[r] = dp[r * Vc * Vc + p];
        float av = A[p];
#pragma unroll
        for (int k = 0; k < TSC; ++k) {
            float acc = sb4[k] + av;
#pragma unroll
            for (int r = 0; r < RELC; ++r) acc += sw4[k * RELC + r] * dv[r];
            sB[(k * 32 + i) * XSROW + j] = f2bf(acc);
        }
    }
    __syncthreads();

    // phase 3: MFMA. wave w owns m-tiles {2w,2w+1}; both n-tiles.
    int wv = tid >> 6, lane = tid & 63, lr = lane & 15, q = lane >> 4;
    f32x4 acc[2][2];
#pragma unroll
    for (int mi = 0; mi < 2; ++mi)
#pragma unroll
        for (int ni = 0; ni < 2; ++ni) acc[mi][ni] = (f32x4)0.0f;

    for (int k = 0; k < TSC; ++k) {
        int r0 = (wv * 2) * 16 + lr + k;
        bf16x8 a0 = ldfrag(xs + r0 * XSROW, q * 4);
        bf16x8 a1 = ldfrag(xs + (r0 + 16) * XSROW, q * 4);
        bf16x8 bb0 = ldfrag(sB + (k * 32 + lr) * XSROW, q * 4);
        bf16x8 bb1 = ldfrag(sB + (k * 32 + 16 + lr) * XSROW, q * 4);
        acc[0][0] = __builtin_amdgcn_mfma_f32_16x16x32_bf16(a0, bb0, acc[0][0], 0, 0, 0);
        acc[0][1] = __builtin_amdgcn_mfma_f32_16x16x32_bf16(a0, bb1, acc[0][1], 0, 0, 0);
        acc[1][0] = __builtin_amdgcn_mfma_f32_16x16x32_bf16(a1, bb0, acc[1][0], 0, 0, 0);
        acc[1][1] = __builtin_amdgcn_mfma_f32_16x16x32_bf16(a1, bb1, acc[1][1], 0, 0, 0);
    }

    // epilogue: D row = q*4+reg (t), col = lr (i); store z bf16 [bc][t][i]
    ushort* zp = z + (size_t)bc * Tc * Vc;
#pragma unroll
    for (int mi = 0; mi < 2; ++mi) {
        int t0 = (wv * 2 + mi) * 16 + q * 4;
#pragma unroll
        for (int ni = 0; ni < 2; ++ni) {
            int i = ni * 16 + lr;
            if (i < Vc) {
#pragma unroll
                for (int r = 0; r < 4; ++r)
                    zp[(t0 + r) * Vc + i] = f2bf(acc[mi][ni][r]);
            }
        }
    }
}

// ---------------- K4: conv3 via MFMA: out[col,o] = sum_c z[col,c]*w3[o,c] -----
#define SZROW 70     // 35 dwords
#define COLT 256
__global__ __launch_bounds__(256, 2) void k_conv3(const ushort* __restrict__ z,
                                                  const float* __restrict__ w3,
                                                  const float* __restrict__ b3,
                                                  float* __restrict__ out) {
    int b = blockIdx.y;
    int col0 = blockIdx.x * COLT;
    __shared__ ushort sz[COLT * SZROW];    // 35.8 KB, z-tile transposed [col][c]
    __shared__ ushort sw3[OUTC * SZROW];   // 9.0 KB, w3 bf16 [o][c]
    int tid = threadIdx.x;

    for (int idx = tid; idx < OUTC * Cc; idx += 256)
        sw3[(idx >> 6) * SZROW + (idx & 63)] = f2bf(w3[idx]);

    const ushort* zb = z + (size_t)b * Cc * Tc * Vc;
#pragma unroll
    for (int rep = 0; rep < 8; ++rep) {
        int it = rep * 256 + tid;
        int cc = it >> 5, ch = it & 31;
        int col = ch * 8, gcol = col0 + col;
        ushort vals[8];
        if (gcol < Tc * Vc) {
            const uint4* src = (const uint4*)(zb + (size_t)cc * Tc * Vc + gcol);
            uint4 u = *src;
            uint ua[4] = {u.x, u.y, u.z, u.w};
#pragma unroll
            for (int e = 0; e < 8; ++e) vals[e] = (ushort)(ua[e >> 1] >> ((e & 1) * 16));
        } else {
#pragma unroll
            for (int e = 0; e < 8; ++e) vals[e] = 0;
        }
#pragma unroll
        for (int e = 0; e < 8; ++e) sz[(col + e) * SZROW + cc] = vals[e];
    }
    __syncthreads();

    int wv = tid >> 6, lane = tid & 63, lr = lane & 15, q = lane >> 4;
    f32x4 acc[4][4];
#pragma unroll
    for (int mi = 0; mi < 4; ++mi)
#pragma unroll
        for (int ni = 0; ni < 4; ++ni) acc[mi][ni] = (f32x4)0.0f;

#pragma unroll
    for (int ks = 0; ks < 2; ++ks) {
        bf16x8 a[4], bb[4];
#pragma unroll
        for (int mi = 0; mi < 4; ++mi)
            a[mi] = ldfrag(sz + ((wv * 4 + mi) * 16 + lr) * SZROW, ks * 16 + q * 4);
#pragma unroll
        for (int ni = 0; ni < 4; ++ni)
            bb[ni] = ldfrag(sw3 + (ni * 16 + lr) * SZROW, ks * 16 + q * 4);
#pragma unroll
        for (int mi = 0; mi < 4; ++mi)
#pragma unroll
            for (int ni = 0; ni < 4; ++ni)
                acc[mi][ni] = __builtin_amdgcn_mfma_f32_16x16x32_bf16(a[mi], bb[ni], acc[mi][ni], 0, 0, 0);
    }

    // store: lane holds out[col = col0+mt*16+q*4+reg][o = ni*16+lr], float4 along col
#pragma unroll
    for (int ni = 0; ni < 4; ++ni) {
        int o = ni * 16 + lr;
        float bias = b3[o];
        float* ob = out + ((size_t)b * OUTC + o) * Tc * Vc;
#pragma unroll
        for (int mi = 0; mi < 4; ++mi) {
            int cb = col0 + (wv * 4 + mi) * 16 + q * 4;
            if (cb < Tc * Vc) {
                float4 st = {acc[mi][ni][0] + bias, acc[mi][ni][1] + bias,
                             acc[mi][ni][2] + bias, acc[mi][ni][3] + bias};
                *(float4*)(ob + cb) = st;
            }
        }
    }
}

extern "C" void kernel_launch(void* const* d_in, const int* in_sizes, int n_in,
                              void* d_out, int out_size, void* d_ws, size_t ws_size,
                              hipStream_t stream) {
    const float* x  = (const float*)d_in[0];
    const float* A  = (const float*)d_in[1];
    const float* w1 = (const float*)d_in[2];
    const float* b1 = (const float*)d_in[3];
    const float* w2 = (const float*)d_in[4];
    const float* b2 = (const float*)d_in[5];
    const float* w3 = (const float*)d_in[6];
    const float* b3 = (const float*)d_in[7];
    const float* w4 = (const float*)d_in[8];
    const float* b4 = (const float*)d_in[9];
    float* out = (float*)d_out;

    float* ws = (float*)d_ws;
    float* xm = ws;                                  // 51200 floats
    float* dd = ws + (size_t)Bc * Cc * Vc;           // 160000 floats
    ushort* zz = (ushort*)(ws + 211200);             // B*C*T*V bf16 (13.1 MB)

    k_mean<<<Bc * Cc, 256, 0, stream>>>(x, xm);
    k_rel<<<Bc, 256, 0, stream>>>(xm, w1, b1, w2, b2, dd);
    k_dynconv<<<Bc * Cc, 256, 0, stream>>>(x, dd, w4, b4, A, zz);
    k_conv3<<<dim3((Tc * Vc + COLT - 1) / COLT, Bc), 256, 0, stream>>>(zz, w3, b3, out);
}

// Round 8
// 131.688 us; speedup vs baseline: 1.5966x; 1.0192x over previous
//
#include <hip/hip_runtime.h>
#include <math.h>

#define Bc 32
#define Cc 64
#define Tc 128
#define Vc 25
#define OUTC 64
#define RELC 8
#define TSC 9

typedef __bf16 bf16x8 __attribute__((ext_vector_type(8)));
typedef float f32x4 __attribute__((ext_vector_type(4)));

static __device__ __forceinline__ ushort f2bf(float f) {
    union { float f; uint u; } v; v.f = f;
    uint u = v.u;
    u += 0x7fff + ((u >> 16) & 1);   // RNE
    return (ushort)(u >> 16);
}

static __device__ __forceinline__ float bf2f(uint bits) {
    union { uint u; float f; } v; v.u = bits << 16;
    return v.f;
}

// load 8 bf16 (4 dwords) from an LDS row at dword offset dwoff; rows are
// padded to odd dword strides so the 4 b32 phases are ~2-way (free) on banks
static __device__ __forceinline__ bf16x8 ldfrag(const ushort* row, int dwoff) {
    const uint* p = (const uint*)row + dwoff;
    uint4 u;
    u.x = p[0]; u.y = p[1]; u.z = p[2]; u.w = p[3];
    return __builtin_bit_cast(bf16x8, u);
}

// ---------------- K1: xm[b,c,v] = mean_t x[b,c,t,v] ----------------
__global__ __launch_bounds__(256) void k_mean(const float* __restrict__ x,
                                              float* __restrict__ xm) {
    int bc = blockIdx.x;
    int v  = threadIdx.x & 31;
    int tg = threadIdx.x >> 5;
    const float* xp = x + (size_t)bc * Tc * Vc;
    float s = 0.f;
    if (v < Vc) {
        for (int t = tg; t < Tc; t += 8) s += xp[t * Vc + v];
    }
    __shared__ float red[8][32];
    red[tg][v] = s;
    __syncthreads();
    if (tg == 0 && v < Vc) {
        float tot = 0.f;
#pragma unroll
        for (int g = 0; g < 8; ++g) tot += red[g][v];
        xm[bc * Vc + v] = tot * (1.0f / Tc);
    }
}

// ---------------- K2: dT[b, j*25+i, r] = bf16(tanh(x1[b,r,j] - x2[b,r,i])) ----
// block = (b, r); 256 blocks. Transposed bf16 layout so dynconv phase-2 reads
// one dwordx4 per (j,i) point instead of 8 scalar dword loads.
__global__ __launch_bounds__(256) void k_rel(const float* __restrict__ xm,
                                             const float* __restrict__ w1,
                                             const float* __restrict__ b1,
                                             const float* __restrict__ w2,
                                             const float* __restrict__ b2,
                                             ushort* __restrict__ dT) {
    int b = blockIdx.x >> 3, r = blockIdx.x & 7;
    __shared__ float sxm[Cc * Vc];
    __shared__ float s1[Vc], s2[Vc];
    int tid = threadIdx.x;
    for (int idx = tid; idx < Cc * Vc; idx += 256)
        sxm[idx] = xm[(size_t)b * Cc * Vc + idx];
    __syncthreads();
    if (tid < 2 * Vc) {
        int which = tid / Vc, v = tid % Vc;
        const float* w = which ? w2 : w1;
        float acc = which ? b2[r] : b1[r];
        for (int c = 0; c < Cc; ++c) acc += w[r * Cc + c] * sxm[c * Vc + v];
        (which ? s2 : s1)[v] = acc;
    }
    __syncthreads();
    ushort* dp = dT + (size_t)b * Vc * Vc * RELC + r;
    for (int p = tid; p < Vc * Vc; p += 256) {
        int j = p / Vc, i = p % Vc;
        dp[p * RELC] = f2bf(tanhf(s1[j] - s2[i]));
    }
}

// ---------------- K3: dynconv via MFMA over 9 shifted GEMMs -------------------
// z[t,i] = sum_k sum_j xs[t+k, j] * W[j,i,k]; one 16x16x32 K-step per shift k.
#define XSROW 38     // 19 dwords: odd-dword row stride -> ~2-way banks
#define XSROWS 136
__global__ __launch_bounds__(256, 4) void k_dynconv(const float* __restrict__ x,
                                                    const ushort* __restrict__ dT,
                                                    const float* __restrict__ w4,
                                                    const float* __restrict__ b4,
                                                    const float* __restrict__ A,
                                                    ushort* __restrict__ z) {
    int bc = blockIdx.x;
    int b = bc / Cc, c = bc % Cc;
    __shared__ ushort xs[XSROWS * XSROW];     // 10.3 KB, padded x in bf16
    __shared__ ushort sB[TSC * 32 * XSROW];   // 21.9 KB, W[j,i,k] as [k][i][j]
    __shared__ float sw4[TSC * RELC];
    __shared__ float sb4[TSC];
    int tid = threadIdx.x;

    // phase 1: zero sB; stage xs (bf16 pairs); load w4/b4 slices
    uint* sBu = (uint*)sB;
    for (int idx = tid; idx < TSC * 32 * (XSROW / 2); idx += 256) sBu[idx] = 0;
    const float* xp = x + (size_t)bc * Tc * Vc;
    uint* xsu = (uint*)xs;
    for (int idx = tid; idx < XSROWS * (XSROW / 2); idx += 256) {
        int row = idx / (XSROW / 2), pr = idx % (XSROW / 2);
        int j0 = pr * 2;
        float f0 = 0.f, f1 = 0.f;
        if (row >= TSC - 1) {
            const float* xr = xp + (row - (TSC - 1)) * Vc;
            if (j0 < Vc) f0 = xr[j0];
            if (j0 + 1 < Vc) f1 = xr[j0 + 1];
        }
        xsu[idx] = (uint)f2bf(f0) | ((uint)f2bf(f1) << 16);
    }
    if (tid < TSC * RELC) sw4[tid] = w4[(c * TSC + tid / RELC) * RELC + tid % RELC];
    if (tid < TSC) sb4[tid] = b4[c * TSC + tid];
    __syncthreads();

    // phase 2: build sB[k][i][j] = b4 + A[j,i] + sum_r w4[k,r]*d[r,j,i]
    const ushort* dp = dT + (size_t)b * Vc * Vc * RELC;
    for (int p = tid; p < Vc * Vc; p += 256) {
        int j = p / Vc, i = p % Vc;
        uint4 u = *(const uint4*)(dp + p * RELC);
        uint ua[4] = {u.x, u.y, u.z, u.w};
        float dv[RELC];
#pragma unroll
        for (int e = 0; e < RELC; ++e)
            dv[e] = bf2f((ua[e >> 1] >> ((e & 1) * 16)) & 0xffffu);
        float av = A[p];
#pragma unroll
        for (int k = 0; k < TSC; ++k) {
            float acc = sb4[k] + av;
#pragma unroll
            for (int r = 0; r < RELC; ++r) acc += sw4[k * RELC + r] * dv[r];
            sB[(k * 32 + i) * XSROW + j] = f2bf(acc);
        }
    }
    __syncthreads();

    // phase 3: MFMA. wave w owns m-tiles {2w,2w+1}; both n-tiles.
    int wv = tid >> 6, lane = tid & 63, lr = lane & 15, q = lane >> 4;
    f32x4 acc[2][2];
#pragma unroll
    for (int mi = 0; mi < 2; ++mi)
#pragma unroll
        for (int ni = 0; ni < 2; ++ni) acc[mi][ni] = (f32x4)0.0f;

#pragma unroll
    for (int k = 0; k < TSC; ++k) {
        int r0 = (wv * 2) * 16 + lr + k;
        bf16x8 a0 = ldfrag(xs + r0 * XSROW, q * 4);
        bf16x8 a1 = ldfrag(xs + (r0 + 16) * XSROW, q * 4);
        bf16x8 bb0 = ldfrag(sB + (k * 32 + lr) * XSROW, q * 4);
        bf16x8 bb1 = ldfrag(sB + (k * 32 + 16 + lr) * XSROW, q * 4);
        acc[0][0] = __builtin_amdgcn_mfma_f32_16x16x32_bf16(a0, bb0, acc[0][0], 0, 0, 0);
        acc[0][1] = __builtin_amdgcn_mfma_f32_16x16x32_bf16(a0, bb1, acc[0][1], 0, 0, 0);
        acc[1][0] = __builtin_amdgcn_mfma_f32_16x16x32_bf16(a1, bb0, acc[1][0], 0, 0, 0);
        acc[1][1] = __builtin_amdgcn_mfma_f32_16x16x32_bf16(a1, bb1, acc[1][1], 0, 0, 0);
    }

    // epilogue: D row = q*4+reg (t), col = lr (i); store z bf16 [bc][t][i]
    ushort* zp = z + (size_t)bc * Tc * Vc;
#pragma unroll
    for (int mi = 0; mi < 2; ++mi) {
        int t0 = (wv * 2 + mi) * 16 + q * 4;
#pragma unroll
        for (int ni = 0; ni < 2; ++ni) {
            int i = ni * 16 + lr;
            if (i < Vc) {
#pragma unroll
                for (int r = 0; r < 4; ++r)
                    zp[(t0 + r) * Vc + i] = f2bf(acc[mi][ni][r]);
            }
        }
    }
}

// ---------------- K4: conv3 via MFMA: out[col,o] = sum_c z[col,c]*w3[o,c] -----
#define SZROW 70     // 35 dwords: odd-dword stride
#define COLT 128
__global__ __launch_bounds__(256, 5) void k_conv3(const ushort* __restrict__ z,
                                                  const float* __restrict__ w3,
                                                  const float* __restrict__ b3,
                                                  float* __restrict__ out) {
    int b = blockIdx.y;
    int col0 = blockIdx.x * COLT;
    __shared__ ushort sz[COLT * SZROW];    // 17.9 KB, z-tile transposed [col][c]
    __shared__ ushort sw3[OUTC * SZROW];   // 9.0 KB, w3 bf16 [o][c]
    int tid = threadIdx.x;

    for (int idx = tid; idx < OUTC * Cc; idx += 256)
        sw3[(idx >> 6) * SZROW + (idx & 63)] = f2bf(w3[idx]);

    const ushort* zb = z + (size_t)b * Cc * Tc * Vc;
#pragma unroll
    for (int rep = 0; rep < 4; ++rep) {
        int it = rep * 256 + tid;            // 1024 tasks: 64 c x 16 col-chunks
        int cc = it >> 4, ch = it & 15;
        int col = ch * 8;
        const uint4* src = (const uint4*)(zb + (size_t)cc * Tc * Vc + col0 + col);
        uint4 u = *src;
        uint ua[4] = {u.x, u.y, u.z, u.w};
#pragma unroll
        for (int e = 0; e < 8; ++e)
            sz[(col + e) * SZROW + cc] = (ushort)(ua[e >> 1] >> ((e & 1) * 16));
    }
    __syncthreads();

    int wv = tid >> 6, lane = tid & 63, lr = lane & 15, q = lane >> 4;
    f32x4 acc[2][4];
#pragma unroll
    for (int mi = 0; mi < 2; ++mi)
#pragma unroll
        for (int ni = 0; ni < 4; ++ni) acc[mi][ni] = (f32x4)0.0f;

#pragma unroll
    for (int ks = 0; ks < 2; ++ks) {
        bf16x8 a[2], bb[4];
#pragma unroll
        for (int mi = 0; mi < 2; ++mi)
            a[mi] = ldfrag(sz + ((wv * 2 + mi) * 16 + lr) * SZROW, ks * 16 + q * 4);
#pragma unroll
        for (int ni = 0; ni < 4; ++ni)
            bb[ni] = ldfrag(sw3 + (ni * 16 + lr) * SZROW, ks * 16 + q * 4);
#pragma unroll
        for (int mi = 0; mi < 2; ++mi)
#pragma unroll
            for (int ni = 0; ni < 4; ++ni)
                acc[mi][ni] = __builtin_amdgcn_mfma_f32_16x16x32_bf16(a[mi], bb[ni], acc[mi][ni], 0, 0, 0);
    }

    // store: lane holds out[col = col0+mt*16+q*4+reg][o = ni*16+lr], float4 along col
#pragma unroll
    for (int ni = 0; ni < 4; ++ni) {
        int o = ni * 16 + lr;
        float bias = b3[o];
        float* ob = out + ((size_t)b * OUTC + o) * Tc * Vc;
#pragma unroll
        for (int mi = 0; mi < 2; ++mi) {
            int cb = col0 + (wv * 2 + mi) * 16 + q * 4;
            float4 st = {acc[mi][ni][0] + bias, acc[mi][ni][1] + bias,
                         acc[mi][ni][2] + bias, acc[mi][ni][3] + bias};
            *(float4*)(ob + cb) = st;
        }
    }
}

extern "C" void kernel_launch(void* const* d_in, const int* in_sizes, int n_in,
                              void* d_out, int out_size, void* d_ws, size_t ws_size,
                              hipStream_t stream) {
    const float* x  = (const float*)d_in[0];
    const float* A  = (const float*)d_in[1];
    const float* w1 = (const float*)d_in[2];
    const float* b1 = (const float*)d_in[3];
    const float* w2 = (const float*)d_in[4];
    const float* b2 = (const float*)d_in[5];
    const float* w3 = (const float*)d_in[6];
    const float* b3 = (const float*)d_in[7];
    const float* w4 = (const float*)d_in[8];
    const float* b4 = (const float*)d_in[9];
    float* out = (float*)d_out;

    float* ws = (float*)d_ws;
    float* xm = ws;                                  // 51200 floats
    ushort* dT = (ushort*)(ws + 51200);              // B*625*8 bf16 (320 KB)
    ushort* zz = (ushort*)(ws + 51200 + 80000);      // B*C*T*V bf16 (13.1 MB)

    k_mean<<<Bc * Cc, 256, 0, stream>>>(x, xm);
    k_rel<<<Bc * RELC, 256, 0, stream>>>(xm, w1, b1, w2, b2, dT);
    k_dynconv<<<Bc * Cc, 256, 0, stream>>>(x, dT, w4, b4, A, zz);
    k_conv3<<<dim3((Tc * Vc) / COLT, Bc), 256, 0, stream>>>(zz, w3, b3, out);
}

// Round 9
// 131.584 us; speedup vs baseline: 1.5979x; 1.0008x over previous
//
#include <hip/hip_runtime.h>
#include <math.h>

#define Bc 32
#define Cc 64
#define Tc 128
#define Vc 25
#define OUTC 64
#define RELC 8
#define TSC 9

typedef __bf16 bf16x8 __attribute__((ext_vector_type(8)));
typedef float f32x4 __attribute__((ext_vector_type(4)));

static __device__ __forceinline__ ushort f2bf(float f) {
    union { float f; uint u; } v; v.f = f;
    uint u = v.u;
    u += 0x7fff + ((u >> 16) & 1);   // RNE
    return (ushort)(u >> 16);
}

static __device__ __forceinline__ float bf2f(uint bits) {
    union { uint u; float f; } v; v.u = bits << 16;
    return v.f;
}

// load 8 bf16 (4 dwords) from an LDS row at dword offset dwoff; rows are
// padded to odd dword strides so the 4 b32 phases are ~2-way (free) on banks
static __device__ __forceinline__ bf16x8 ldfrag(const ushort* row, int dwoff) {
    const uint* p = (const uint*)row + dwoff;
    uint4 u;
    u.x = p[0]; u.y = p[1]; u.z = p[2]; u.w = p[3];
    return __builtin_bit_cast(bf16x8, u);
}

// ---------------- K1: xm[b,c,v] = mean_t x[b,c,t,v] ----------------
__global__ __launch_bounds__(256) void k_mean(const float* __restrict__ x,
                                              float* __restrict__ xm) {
    int bc = blockIdx.x;
    int v  = threadIdx.x & 31;
    int tg = threadIdx.x >> 5;
    const float* xp = x + (size_t)bc * Tc * Vc;
    float s = 0.f;
    if (v < Vc) {
        for (int t = tg; t < Tc; t += 8) s += xp[t * Vc + v];
    }
    __shared__ float red[8][32];
    red[tg][v] = s;
    __syncthreads();
    if (tg == 0 && v < Vc) {
        float tot = 0.f;
#pragma unroll
        for (int g = 0; g < 8; ++g) tot += red[g][v];
        xm[bc * Vc + v] = tot * (1.0f / Tc);
    }
}

// ---------------- K2: dT[b, j*25+i, r] = bf16(tanh(x1[b,r,j] - x2[b,r,i])) ----
__global__ __launch_bounds__(256) void k_rel(const float* __restrict__ xm,
                                             const float* __restrict__ w1,
                                             const float* __restrict__ b1,
                                             const float* __restrict__ w2,
                                             const float* __restrict__ b2,
                                             ushort* __restrict__ dT) {
    int b = blockIdx.x >> 3, r = blockIdx.x & 7;
    __shared__ float sxm[Cc * Vc];
    __shared__ float s1[Vc], s2[Vc];
    int tid = threadIdx.x;
    for (int idx = tid; idx < Cc * Vc; idx += 256)
        sxm[idx] = xm[(size_t)b * Cc * Vc + idx];
    __syncthreads();
    if (tid < 2 * Vc) {
        int which = tid / Vc, v = tid % Vc;
        const float* w = which ? w2 : w1;
        float acc = which ? b2[r] : b1[r];
        for (int c = 0; c < Cc; ++c) acc += w[r * Cc + c] * sxm[c * Vc + v];
        (which ? s2 : s1)[v] = acc;
    }
    __syncthreads();
    ushort* dp = dT + (size_t)b * Vc * Vc * RELC + r;
    for (int p = tid; p < Vc * Vc; p += 256) {
        int j = p / Vc, i = p % Vc;
        dp[p * RELC] = f2bf(tanhf(s1[j] - s2[i]));
    }
}

// ---------------- K3: dynconv via MFMA over 9 shifted GEMMs -------------------
// z[t,i] = sum_k sum_j xs[t+k, j] * W[j,i,k]; one 16x16x32 K-step per shift k.
// MFMA frags read only dwords 0..15 of each 19-dword row, so only ushorts
// 25..31 (K-pad) and the never-written rows need zeroing — not the full tile.
#define XSROW 38     // 19 dwords: odd-dword row stride -> ~2-way banks
#define XSROWS 136
__global__ __launch_bounds__(256, 4) void k_dynconv(const float* __restrict__ x,
                                                    const ushort* __restrict__ dT,
                                                    const float* __restrict__ w4,
                                                    const float* __restrict__ b4,
                                                    const float* __restrict__ A,
                                                    ushort* __restrict__ z) {
    int bc = blockIdx.x;
    int b = bc / Cc, c = bc % Cc;
    __shared__ ushort xs[XSROWS * XSROW];     // 10.3 KB, padded x in bf16
    __shared__ ushort sB[TSC * 32 * XSROW];   // 21.9 KB, W[j,i,k] as [k][i][j]
    __shared__ float sw4[TSC * RELC];
    __shared__ float sb4[TSC];
    int tid = threadIdx.x;
    uint* sBu = (uint*)sB;
    uint* xsu = (uint*)xs;

    // ---- phase 1a: minimal sB zeroing ----
    // rows i in [25,32) per k (never written by phase 2, read by bb1): dwords 0..15
    for (int idx = tid; idx < 63 * 16; idx += 256) {
        int rr = idx >> 4, dw = idx & 15;
        int k = rr / 7, i = 25 + rr % 7;
        sBu[(k * 32 + i) * 19 + dw] = 0;
    }
    // rows i in [0,25): K-pad ushorts 25..31 only (disjoint bytes from data)
    for (int idx = tid; idx < 225 * 4; idx += 256) {
        int rr = idx >> 2, w = idx & 3;
        int row = (rr / 25) * 32 + (rr % 25);
        if (w == 0) sB[row * XSROW + 25] = 0;
        else        sBu[row * 19 + 12 + w] = 0;
    }
    // ---- phase 1b: xs zero pad ----
    // causal-pad rows 0..7: dwords 0..15
    for (int idx = tid; idx < 8 * 16; idx += 256) {
        int r = idx >> 4, dw = idx & 15;
        xsu[r * 19 + dw] = 0;
    }
    // data rows 8..135: K-pad ushorts 25..31
    for (int idx = tid; idx < 128 * 4; idx += 256) {
        int r = 8 + (idx >> 2), w = idx & 3;
        if (w == 0) xs[r * XSROW + 25] = 0;
        else        xsu[r * 19 + 12 + w] = 0;
    }
    // ---- phase 1c: stage x via linear float4 reads (800 loads vs 5168 scalar)
    const float4* xp4 = (const float4*)(x + (size_t)bc * Tc * Vc);
    for (int idx = tid; idx < 800; idx += 256) {
        float4 f = xp4[idx];
        int f0 = idx * 4;
        float fe[4] = {f.x, f.y, f.z, f.w};
#pragma unroll
        for (int e = 0; e < 4; ++e) {
            int ff = f0 + e;
            int t = ff / 25, cl = ff - t * 25;
            xs[(t + 8) * XSROW + cl] = f2bf(fe[e]);
        }
    }
    if (tid < TSC * RELC) sw4[tid] = w4[(c * TSC + tid / RELC) * RELC + tid % RELC];
    if (tid < TSC) sb4[tid] = b4[c * TSC + tid];
    __syncthreads();

    // phase 2: build sB[k][i][j] = b4 + A[j,i] + sum_r w4[k,r]*d[r,j,i]
    const ushort* dp = dT + (size_t)b * Vc * Vc * RELC;
    for (int p = tid; p < Vc * Vc; p += 256) {
        int j = p / Vc, i = p % Vc;
        uint4 u = *(const uint4*)(dp + p * RELC);
        uint ua[4] = {u.x, u.y, u.z, u.w};
        float dv[RELC];
#pragma unroll
        for (int e = 0; e < RELC; ++e)
            dv[e] = bf2f((ua[e >> 1] >> ((e & 1) * 16)) & 0xffffu);
        float av = A[p];
#pragma unroll
        for (int k = 0; k < TSC; ++k) {
            float acc = sb4[k] + av;
#pragma unroll
            for (int r = 0; r < RELC; ++r) acc += sw4[k * RELC + r] * dv[r];
            sB[(k * 32 + i) * XSROW + j] = f2bf(acc);
        }
    }
    __syncthreads();

    // phase 3: MFMA. wave w owns m-tiles {2w,2w+1}; both n-tiles.
    int wv = tid >> 6, lane = tid & 63, lr = lane & 15, q = lane >> 4;
    f32x4 acc[2][2];
#pragma unroll
    for (int mi = 0; mi < 2; ++mi)
#pragma unroll
        for (int ni = 0; ni < 2; ++ni) acc[mi][ni] = (f32x4)0.0f;

#pragma unroll
    for (int k = 0; k < TSC; ++k) {
        int r0 = (wv * 2) * 16 + lr + k;
        bf16x8 a0 = ldfrag(xs + r0 * XSROW, q * 4);
        bf16x8 a1 = ldfrag(xs + (r0 + 16) * XSROW, q * 4);
        bf16x8 bb0 = ldfrag(sB + (k * 32 + lr) * XSROW, q * 4);
        bf16x8 bb1 = ldfrag(sB + (k * 32 + 16 + lr) * XSROW, q * 4);
        acc[0][0] = __builtin_amdgcn_mfma_f32_16x16x32_bf16(a0, bb0, acc[0][0], 0, 0, 0);
        acc[0][1] = __builtin_amdgcn_mfma_f32_16x16x32_bf16(a0, bb1, acc[0][1], 0, 0, 0);
        acc[1][0] = __builtin_amdgcn_mfma_f32_16x16x32_bf16(a1, bb0, acc[1][0], 0, 0, 0);
        acc[1][1] = __builtin_amdgcn_mfma_f32_16x16x32_bf16(a1, bb1, acc[1][1], 0, 0, 0);
    }

    // epilogue: D row = q*4+reg (t), col = lr (i); store z bf16 [bc][t][i]
    ushort* zp = z + (size_t)bc * Tc * Vc;
#pragma unroll
    for (int mi = 0; mi < 2; ++mi) {
        int t0 = (wv * 2 + mi) * 16 + q * 4;
#pragma unroll
        for (int ni = 0; ni < 2; ++ni) {
            int i = ni * 16 + lr;
            if (i < Vc) {
#pragma unroll
                for (int r = 0; r < 4; ++r)
                    zp[(t0 + r) * Vc + i] = f2bf(acc[mi][ni][r]);
            }
        }
    }
}

// ---------------- K4: conv3 via MFMA: out[col,o] = sum_c z[col,c]*w3[o,c] -----
// transpose staging packs 2 c's per ds_write_b32; lane map gives 16 cp x 4 colg
// per wave -> bank residues uniformly 2-way (free per m136)
#define SZROW 70     // 35 dwords: odd-dword stride
#define COLT 128
__global__ __launch_bounds__(256, 5) void k_conv3(const ushort* __restrict__ z,
                                                  const float* __restrict__ w3,
                                                  const float* __restrict__ b3,
                                                  float* __restrict__ out) {
    int b = blockIdx.y;
    int col0 = blockIdx.x * COLT;
    __shared__ ushort sz[COLT * SZROW];    // 17.9 KB, z-tile transposed [col][c]
    __shared__ ushort sw3[OUTC * SZROW];   // 9.0 KB, w3 bf16 [o][c]
    int tid = threadIdx.x;

    for (int idx = tid; idx < OUTC * Cc; idx += 256)
        sw3[(idx >> 6) * SZROW + (idx & 63)] = f2bf(w3[idx]);

    const ushort* zb = z + (size_t)b * Cc * Tc * Vc;
    uint* szd = (uint*)sz;
#pragma unroll
    for (int s = 0; s < 2; ++s) {
        int task = tid + 256 * s;            // 512 tasks: 32 c-pairs x 16 col-groups
        int cp = (task & 15) + 16 * s;       // c-pair 0..31
        int colg = (task >> 4) & 15;         // col-group 0..15
        int c0 = cp * 2, col = colg * 8;
        uint4 u0 = *(const uint4*)(zb + (size_t)(c0 + 0) * Tc * Vc + col0 + col);
        uint4 u1 = *(const uint4*)(zb + (size_t)(c0 + 1) * Tc * Vc + col0 + col);
        uint a0[4] = {u0.x, u0.y, u0.z, u0.w};
        uint a1[4] = {u1.x, u1.y, u1.z, u1.w};
#pragma unroll
        for (int e = 0; e < 8; ++e) {
            uint v0 = (a0[e >> 1] >> ((e & 1) * 16)) & 0xffffu;
            uint v1 = (a1[e >> 1] >> ((e & 1) * 16)) & 0xffffu;
            szd[(col + e) * (SZROW / 2) + cp] = v0 | (v1 << 16);
        }
    }
    __syncthreads();

    int wv = tid >> 6, lane = tid & 63, lr = lane & 15, q = lane >> 4;
    f32x4 acc[2][4];
#pragma unroll
    for (int mi = 0; mi < 2; ++mi)
#pragma unroll
        for (int ni = 0; ni < 4; ++ni) acc[mi][ni] = (f32x4)0.0f;

#pragma unroll
    for (int ks = 0; ks < 2; ++ks) {
        bf16x8 a[2], bb[4];
#pragma unroll
        for (int mi = 0; mi < 2; ++mi)
            a[mi] = ldfrag(sz + ((wv * 2 + mi) * 16 + lr) * SZROW, ks * 16 + q * 4);
#pragma unroll
        for (int ni = 0; ni < 4; ++ni)
            bb[ni] = ldfrag(sw3 + (ni * 16 + lr) * SZROW, ks * 16 + q * 4);
#pragma unroll
        for (int mi = 0; mi < 2; ++mi)
#pragma unroll
            for (int ni = 0; ni < 4; ++ni)
                acc[mi][ni] = __builtin_amdgcn_mfma_f32_16x16x32_bf16(a[mi], bb[ni], acc[mi][ni], 0, 0, 0);
    }

    // store: lane holds out[col = col0+mt*16+q*4+reg][o = ni*16+lr], float4 along col
#pragma unroll
    for (int ni = 0; ni < 4; ++ni) {
        int o = ni * 16 + lr;
        float bias = b3[o];
        float* ob = out + ((size_t)b * OUTC + o) * Tc * Vc;
#pragma unroll
        for (int mi = 0; mi < 2; ++mi) {
            int cb = col0 + (wv * 2 + mi) * 16 + q * 4;
            float4 st = {acc[mi][ni][0] + bias, acc[mi][ni][1] + bias,
                         acc[mi][ni][2] + bias, acc[mi][ni][3] + bias};
            *(float4*)(ob + cb) = st;
        }
    }
}

extern "C" void kernel_launch(void* const* d_in, const int* in_sizes, int n_in,
                              void* d_out, int out_size, void* d_ws, size_t ws_size,
                              hipStream_t stream) {
    const float* x  = (const float*)d_in[0];
    const float* A  = (const float*)d_in[1];
    const float* w1 = (const float*)d_in[2];
    const float* b1 = (const float*)d_in[3];
    const float* w2 = (const float*)d_in[4];
    const float* b2 = (const float*)d_in[5];
    const float* w3 = (const float*)d_in[6];
    const float* b3 = (const float*)d_in[7];
    const float* w4 = (const float*)d_in[8];
    const float* b4 = (const float*)d_in[9];
    float* out = (float*)d_out;

    float* ws = (float*)d_ws;
    float* xm = ws;                                  // 51200 floats
    ushort* dT = (ushort*)(ws + 51200);              // B*625*8 bf16 (320 KB)
    ushort* zz = (ushort*)(ws + 51200 + 80000);      // B*C*T*V bf16 (13.1 MB)

    k_mean<<<Bc * Cc, 256, 0, stream>>>(x, xm);
    k_rel<<<Bc * RELC, 256, 0, stream>>>(xm, w1, b1, w2, b2, dT);
    k_dynconv<<<Bc * Cc, 256, 0, stream>>>(x, dT, w4, b4, A, zz);
    k_conv3<<<dim3((Tc * Vc) / COLT, Bc), 256, 0, stream>>>(zz, w3, b3, out);
}